// Round 2
// baseline (22447.298 us; speedup 1.0000x reference)
//
#include <hip/hip_runtime.h>

// GraphMemoryNetwork on MI355X — all reference tensors are float32.
// Structure: 7 small GEMMs (bf16 MFMA, f32 accum) + 3 sequential LSTM scans of
// T=8192 steps (the node axis is a lax.scan). Scans run as a single persistent
// 512-thread workgroup with Whh register-resident as int8 (per-row scales),
// h broadcast through LDS as packed i8, f32 cell state.

typedef __attribute__((ext_vector_type(8))) short short8;   // 8 bf16 (4 VGPRs)
typedef __attribute__((ext_vector_type(4))) float f32x4;

#define LOG2E 1.44269504088896340736f

__device__ __forceinline__ float fast_sigmoid(float x) {
  float e = __builtin_amdgcn_exp2f(-x * LOG2E);
  return __builtin_amdgcn_rcpf(1.0f + e);
}
__device__ __forceinline__ float fast_tanh(float x) {
  float e = __builtin_amdgcn_exp2f(x * (2.0f * LOG2E));   // e^{2x}
  return 1.0f - 2.0f * __builtin_amdgcn_rcpf(e + 1.0f);
}

__device__ __forceinline__ unsigned short f2bf(float x) {  // RNE, no NaN inputs
  unsigned int u = __float_as_uint(x);
  u += 0x7FFFu + ((u >> 16) & 1u);
  return (unsigned short)(u >> 16);
}
__device__ __forceinline__ float bf2f(unsigned short b) {
  return __uint_as_float(((unsigned int)b) << 16);
}

#if __has_builtin(__builtin_amdgcn_sdot4)
#define SDOT4(a, b, c) __builtin_amdgcn_sdot4((a), (b), (c), false)
#else
__device__ __forceinline__ int sdot4_sw(int a, int b, int c) {
  c += ((a << 24) >> 24) * ((b << 24) >> 24);
  c += ((a << 16) >> 24) * ((b << 16) >> 24);
  c += ((a << 8) >> 24) * ((b << 8) >> 24);
  c += (a >> 24) * (b >> 24);
  return c;
}
#define SDOT4(a, b, c) sdot4_sw((a), (b), (c))
#endif

// ---------------------------------------------------------------------------
// GEMM: C[M,N] = A[M,K] * W[N,K]^T + bias0 + bias1.  A,W bf16 row-major
// (ushort). biases f32. 128x128 tile, BK=64, 4 waves (2x2), 16x16x32 bf16
// MFMA, reg-staged LDS.  K % 64 == 0.
// ---------------------------------------------------------------------------
__global__ __launch_bounds__(256) void gemm_bt(
    const unsigned short* __restrict__ A, int lda,
    const unsigned short* __restrict__ W, int ldw,
    const float* __restrict__ bias0,
    const float* __restrict__ bias1,
    void* __restrict__ C, int ldc, int c_f32, int K)
{
  __shared__ unsigned short As[128 * 64];
  __shared__ unsigned short Bs[128 * 64];
  const int tid = threadIdx.x;
  const int lane = tid & 63;
  const int w = tid >> 6;
  const int wm = w >> 1, wn = w & 1;
  const int bm = blockIdx.y * 128, bn = blockIdx.x * 128;

  f32x4 acc[4][4];
#pragma unroll
  for (int m = 0; m < 4; ++m)
#pragma unroll
    for (int n = 0; n < 4; ++n)
      acc[m][n] = (f32x4){0.f, 0.f, 0.f, 0.f};

  for (int k0 = 0; k0 < K; k0 += 64) {
    uint4 va[4], vb[4];
#pragma unroll
    for (int i = 0; i < 4; ++i) {
      int c = i * 256 + tid;                  // 16B chunk id within 128x64 tile
      va[i] = *(const uint4*)(A + (size_t)(bm + (c >> 3)) * lda + k0 + (c & 7) * 8);
      vb[i] = *(const uint4*)(W + (size_t)(bn + (c >> 3)) * ldw + k0 + (c & 7) * 8);
    }
    __syncthreads();                          // prev-iter LDS reads done
#pragma unroll
    for (int i = 0; i < 4; ++i) {
      int c = i * 256 + tid;
      *(uint4*)&As[c * 8] = va[i];
      *(uint4*)&Bs[c * 8] = vb[i];
    }
    __syncthreads();                          // tile ready
#pragma unroll
    for (int ks = 0; ks < 2; ++ks) {
      short8 a[4], b[4];
#pragma unroll
      for (int m = 0; m < 4; ++m)
        a[m] = *(const short8*)&As[(wm * 64 + m * 16 + (lane & 15)) * 64 + ks * 32 + (lane >> 4) * 8];
#pragma unroll
      for (int n = 0; n < 4; ++n)
        b[n] = *(const short8*)&Bs[(wn * 64 + n * 16 + (lane & 15)) * 64 + ks * 32 + (lane >> 4) * 8];
#pragma unroll
      for (int m = 0; m < 4; ++m)
#pragma unroll
        for (int n = 0; n < 4; ++n)
          acc[m][n] = __builtin_amdgcn_mfma_f32_16x16x32_bf16(a[m], b[n], acc[m][n], 0, 0, 0);
    }
  }

  // epilogue: C/D layout col=lane&15, row=(lane>>4)*4+reg
#pragma unroll
  for (int n = 0; n < 4; ++n) {
    int col = bn + wn * 64 + n * 16 + (lane & 15);
    float bsum = 0.f;
    if (bias0) bsum += bias0[col];
    if (bias1) bsum += bias1[col];
#pragma unroll
    for (int m = 0; m < 4; ++m) {
      int rbase = bm + wm * 64 + m * 16 + ((lane >> 4) * 4);
#pragma unroll
      for (int q = 0; q < 4; ++q) {
        float v = acc[m][n][q] + bsum;
        if (c_f32)
          ((float*)C)[(size_t)(rbase + q) * ldc + col] = v;
        else
          ((unsigned short*)C)[(size_t)(rbase + q) * ldc + col] = f2bf(v);
      }
    }
  }
}

// ---------------------------------------------------------------------------
// f32 -> bf16 conversions
// ---------------------------------------------------------------------------
__global__ void f2bf_flat(const float* __restrict__ src,
                          unsigned short* __restrict__ dst, int n4)
{
  int gid = blockIdx.x * 256 + threadIdx.x;
  if (gid >= n4) return;
  f32x4 v = ((const f32x4*)src)[gid];
  ushort4 o;
  o.x = f2bf(v.x); o.y = f2bf(v.y); o.z = f2bf(v.z); o.w = f2bf(v.w);
  ((ushort4*)dst)[gid] = o;
}

// copy f32 [rows, width] (contig) into bf16 [rows, dstLd] column block
__global__ void f2bf_strided(const float* __restrict__ src,
                             unsigned short* __restrict__ dst, int dstLd,
                             int chunkShift, int total)   // chunks of 4 elems
{
  int gid = blockIdx.x * 256 + threadIdx.x;
  if (gid >= total) return;
  int row = gid >> chunkShift;
  int ch = gid & ((1 << chunkShift) - 1);
  f32x4 v = ((const f32x4*)src)[(size_t)gid];
  ushort4 o;
  o.x = f2bf(v.x); o.y = f2bf(v.y); o.z = f2bf(v.z); o.w = f2bf(v.w);
  *(ushort4*)(dst + (size_t)row * dstLd + ch * 4) = o;
}

// ---------------------------------------------------------------------------
// Quantize LSTM recurrent weights [nrows x 256] f32 -> i8 (packed dwords) +
// per-row scale (max/127). One wave per row.
// ---------------------------------------------------------------------------
__global__ void quant_rows(const float* __restrict__ Wsrc,
                           int* __restrict__ wq, float* __restrict__ scales,
                           int nrows)
{
  int row = blockIdx.x * 4 + (threadIdx.x >> 6);
  if (row >= nrows) return;
  int lane = threadIdx.x & 63;
  float v[4];
  float mx = 0.f;
#pragma unroll
  for (int i = 0; i < 4; ++i) {
    v[i] = Wsrc[(size_t)row * 256 + lane * 4 + i];
    mx = fmaxf(mx, fabsf(v[i]));
  }
#pragma unroll
  for (int d = 32; d >= 1; d >>= 1) mx = fmaxf(mx, __shfl_xor(mx, d));
  float inv = (mx > 0.f) ? 127.f / mx : 0.f;
  int packed = 0;
#pragma unroll
  for (int i = 0; i < 4; ++i) {
    int q = __float2int_rn(v[i] * inv);
    q = max(-127, min(127, q));
    packed |= (q & 0xFF) << (8 * i);
  }
  wq[(size_t)row * 64 + lane] = packed;
  if (lane == 0) scales[row] = mx / 127.f;
}

// ---------------------------------------------------------------------------
// Sequential LSTM scan, T steps, H=256 (4H=1024 gate rows), single workgroup.
// Thread j owns gate rows j and j+512 (j<256: i,g ; j>=256: f,o for unit
// j-256; PyTorch gate order [i,f,g,o]). Whh register-resident as i8 (128
// VGPRs/thread). h broadcast via LDS (packed i8, scale 127). Output h as bf16.
// ---------------------------------------------------------------------------
__global__ __launch_bounds__(512, 2) void lstm_scan(
    const float* __restrict__ xg,     // [T][1024]  (includes bih+bhh)
    const int* __restrict__ wq,       // [1024][64] packed i8
    const float* __restrict__ wsc,    // [1024]
    unsigned short* __restrict__ hs,  // [T][ldh] bf16 output
    int T, int ldh)
{
  const int j = threadIdx.x;
  const int row0 = j, row1 = j + 512;

  int w0[64], w1[64];
#pragma unroll
  for (int k = 0; k < 64; ++k) w0[k] = wq[(size_t)row0 * 64 + k];
#pragma unroll
  for (int k = 0; k < 64; ++k) w1[k] = wq[(size_t)row1 * 64 + k];
  const float s0 = wsc[row0] * (1.f / 127.f);
  const float s1 = wsc[row1] * (1.f / 127.f);

  __shared__ __align__(16) int hq[64];   // h quantized to i8, packed
  __shared__ float ubuf[256];            // i * tanh(g)
  if (j < 64) hq[j] = 0;
  float c = 0.f;                         // cell state (threads 256..511)

  const float* px0 = xg + row0;
  const float* px1 = xg + row1;
  // depth-2 xg register pipeline
  float xA0 = px0[0], xA1 = px1[0];
  float xB0 = px0[1024], xB1 = px1[1024];
  __syncthreads();

  for (int t = 0; t < T; ++t) {
    int tp = (t + 2 < T) ? (t + 2) : (T - 1);
    float xC0 = px0[(size_t)tp * 1024];
    float xC1 = px1[(size_t)tp * 1024];

    int a0a = 0, a0b = 0, a1a = 0, a1b = 0;
    const int4* h4 = (const int4*)hq;
#pragma unroll
    for (int kk = 0; kk < 16; ++kk) {
      int4 hc = h4[kk];                  // uniform ds_read_b128 (broadcast)
      a0a = SDOT4(w0[4 * kk + 0], hc.x, a0a); a1a = SDOT4(w1[4 * kk + 0], hc.x, a1a);
      a0b = SDOT4(w0[4 * kk + 1], hc.y, a0b); a1b = SDOT4(w1[4 * kk + 1], hc.y, a1b);
      a0a = SDOT4(w0[4 * kk + 2], hc.z, a0a); a1a = SDOT4(w1[4 * kk + 2], hc.z, a1a);
      a0b = SDOT4(w0[4 * kk + 3], hc.w, a0b); a1b = SDOT4(w1[4 * kk + 3], hc.w, a1b);
    }
    float p0 = (float)(a0a + a0b) * s0 + xA0;
    float p1 = (float)(a1a + a1b) * s1 + xA1;

    if (j < 256) {
      ubuf[j] = fast_sigmoid(p0) * fast_tanh(p1);   // i * g~
    }
    __syncthreads();   // ubuf ready; all hq reads of this step complete
    if (j >= 256) {
      const int m = j - 256;
      float f = fast_sigmoid(p0);
      float o = fast_sigmoid(p1);
      c = f * c + ubuf[m];
      float h = o * fast_tanh(c);
      hs[(size_t)t * ldh + m] = f2bf(h);
      int q = __float2int_rn(h * 127.f);            // |h|<1 -> |q|<=127
      int q1 = __shfl_down(q, 1);
      int q2 = __shfl_down(q, 2);
      int q3 = __shfl_down(q, 3);
      if ((m & 3) == 0)
        hq[m >> 2] = (q & 0xFF) | ((q1 & 0xFF) << 8) | ((q2 & 0xFF) << 16) | ((q3 & 0xFF) << 24);
    }
    xA0 = xB0; xA1 = xB1; xB0 = xC0; xB1 = xC1;
    __syncthreads();   // hq ready for next step
  }
}

// ---------------------------------------------------------------------------
// pair[n] = [nodes[e0[n]] | nodes[e1[n]]]  (bf16, 16B chunks)
// ---------------------------------------------------------------------------
__global__ void gather_pair(const unsigned short* __restrict__ nodes,
                            const int* __restrict__ edges,
                            unsigned short* __restrict__ pair)
{
  int gid = blockIdx.x * 256 + threadIdx.x;   // over 8192*64 chunks
  int row = gid >> 6;
  int ch = gid & 63;
  int side = ch >> 5;
  int k = ch & 31;
  int src = edges[row * 2 + side];
  uint4 v = ((const uint4*)(nodes + (size_t)src * 256))[k];
  ((uint4*)(pair + (size_t)row * 512))[ch] = v;
}

// ---------------------------------------------------------------------------
extern "C" void kernel_launch(void* const* d_in, const int* in_sizes, int n_in,
                              void* d_out, int out_size, void* d_ws, size_t ws_size,
                              hipStream_t stream)
{
  const float* inputs   = (const float*)d_in[0];
  const int*   edges    = (const int*)d_in[1];
  const float* memory   = (const float*)d_in[2];
  const float* Wi       = (const float*)d_in[3];
  const float* bi       = (const float*)d_in[4];
  const float* Wo       = (const float*)d_in[5];
  const float* bo       = (const float*)d_in[6];
  const float* edge_W   = (const float*)d_in[7];
  const float* edge_b   = (const float*)d_in[8];
  const float* node_Wih = (const float*)d_in[9];
  const float* node_Whh = (const float*)d_in[10];
  const float* node_bih = (const float*)d_in[11];
  const float* node_bhh = (const float*)d_in[12];
  const float* Wm       = (const float*)d_in[13];
  const float* bm       = (const float*)d_in[14];
  const float* cWih     = (const float*)d_in[15];
  const float* cWhh     = (const float*)d_in[16];
  const float* cbih     = (const float*)d_in[17];
  const float* cbhh     = (const float*)d_in[18];

  char* ws = (char*)d_ws;
  float*          xgbuf  = (float*)(ws + 0);                    // [8192,1024] f32
  unsigned short* Xbf    = (unsigned short*)(ws + 33554432);    // [8192,512]  inputs|edge_h
  unsigned short* Xc     = (unsigned short*)(ws + 41943040);    // [8192,640]  inputs|nodes2|memory
  unsigned short* nodes0 = (unsigned short*)(ws + 52428800);    // [8192,256]
  unsigned short* nodesA = (unsigned short*)(ws + 56623104);    // [8192,256]
  unsigned short* PAIR   = (unsigned short*)(ws + 60817408);    // [8192,512]
  unsigned short* hsC    = (unsigned short*)(ws + 69206016);    // [8192,256]
  unsigned short* WiB    = (unsigned short*)(ws + 73400320);    // 65536
  unsigned short* WoB    = (unsigned short*)(ws + 73531392);    // 65536
  unsigned short* eWB    = (unsigned short*)(ws + 73662464);    // 262144
  unsigned short* nWihB  = (unsigned short*)(ws + 74186752);    // 1048576
  unsigned short* WmB    = (unsigned short*)(ws + 76283904);    // 32768
  unsigned short* cWihB  = (unsigned short*)(ws + 76349440);    // 655360
  int*            wqN    = (int*)(ws + 77660160);               // [2048,64]
  int*            wqC    = (int*)(ws + 78184448);               // [1024,64]
  float*          scN    = (float*)(ws + 78446592);             // [2048]
  float*          scC    = (float*)(ws + 78454784);             // [1024]

  float* out0 = (float*)d_out;                // out     [8192,256] f32
  float* out1 = out0 + 8192 * 256;            // memvec  [8192,128] f32

  // --- prep: weight conversions + recurrent-weight quantization ---
  quant_rows<<<512, 256, 0, stream>>>(node_Whh, wqN, scN, 2048);
  quant_rows<<<256, 256, 0, stream>>>(cWhh, wqC, scC, 1024);
  f2bf_flat<<<64, 256, 0, stream>>>(Wi, WiB, 16384);
  f2bf_flat<<<64, 256, 0, stream>>>(Wo, WoB, 16384);
  f2bf_flat<<<256, 256, 0, stream>>>(edge_W, eWB, 65536);
  f2bf_flat<<<1024, 256, 0, stream>>>(node_Wih, nWihB, 262144);
  f2bf_flat<<<32, 256, 0, stream>>>(Wm, WmB, 8192);
  f2bf_flat<<<640, 256, 0, stream>>>(cWih, cWihB, 163840);

  // --- static column blocks (inputs, memory) as bf16 ---
  f2bf_strided<<<2048, 256, 0, stream>>>(inputs, Xbf, 512, 6, 8192 * 64);
  f2bf_strided<<<2048, 256, 0, stream>>>(inputs, Xc, 640, 6, 8192 * 64);
  f2bf_strided<<<1024, 256, 0, stream>>>(memory, Xc + 512, 640, 5, 8192 * 32);

  // --- input layer: nodes0 = inputs @ Wi^T + bi ---
  gemm_bt<<<dim3(2, 64), 256, 0, stream>>>(Xbf, 512, WiB, 256, bi, nullptr,
                                           nodes0, 256, 0, 256);

  // --- relation r = 0 ---
  gather_pair<<<2048, 256, 0, stream>>>(nodes0, edges, PAIR);
  gemm_bt<<<dim3(2, 64), 256, 0, stream>>>(PAIR, 512, eWB, 512, edge_b, nullptr,
                                           Xbf + 256, 512, 0, 512);
  gemm_bt<<<dim3(8, 64), 256, 0, stream>>>(Xbf, 512, nWihB, 512, node_bih, node_bhh,
                                           xgbuf, 1024, 1, 512);
  lstm_scan<<<1, 512, 0, stream>>>(xgbuf, wqN, scN, nodesA, 8192, 256);

  // --- relation r = 1 (LSTM writes straight into Xc[:,256:512]) ---
  gather_pair<<<2048, 256, 0, stream>>>(nodesA, edges, PAIR);
  gemm_bt<<<dim3(2, 64), 256, 0, stream>>>(PAIR, 512, eWB + 256 * 512, 512,
                                           edge_b + 256, nullptr, Xbf + 256, 512, 0, 512);
  gemm_bt<<<dim3(8, 64), 256, 0, stream>>>(Xbf, 512, nWihB + 1024 * 512, 512,
                                           node_bih + 1024, node_bhh + 1024,
                                           xgbuf, 1024, 1, 512);
  lstm_scan<<<1, 512, 0, stream>>>(xgbuf, wqN + 1024 * 64, scN + 1024, Xc + 256, 8192, 640);

  // --- memory vector: nodes2 @ Wm^T + bm  (nodes2 = Xc[:,256:512]) ---
  gemm_bt<<<dim3(1, 64), 256, 0, stream>>>(Xc + 256, 640, WmB, 256, bm, nullptr,
                                           out1, 128, 1, 256);

  // --- controller LSTM ---
  gemm_bt<<<dim3(8, 64), 256, 0, stream>>>(Xc, 640, cWihB, 640, cbih, cbhh,
                                           xgbuf, 1024, 1, 640);
  lstm_scan<<<1, 512, 0, stream>>>(xgbuf, wqC, scC, hsC, 8192, 256);

  // --- output layer ---
  gemm_bt<<<dim3(2, 64), 256, 0, stream>>>(hsC, 256, WoB, 256, bo, nullptr,
                                           out0, 256, 1, 256);
}

// Round 3
// 19977.670 us; speedup vs baseline: 1.1236x; 1.1236x over previous
//
#include <hip/hip_runtime.h>

// GraphMemoryNetwork on MI355X — all reference tensors are float32.
// 7 small GEMMs (bf16 MFMA, f32 accum) + 3 sequential LSTM scans of T=8192
// steps. Scan v2: 512 threads, even/odd lane pairing (even: i,g rows; odd:
// f,o rows), ONE raw s_barrier per step (lgkmcnt-only wait — xg prefetch
// stays in flight), double-buffered i8 h broadcast in LDS, Whh as int8 with
// per-row scales in (hopefully) arch VGPRs.

typedef __attribute__((ext_vector_type(8))) short short8;   // 8 bf16 (4 VGPRs)
typedef __attribute__((ext_vector_type(4))) float f32x4;

#define LOG2E 1.44269504088896340736f

__device__ __forceinline__ float fast_sigmoid(float x) {
  float e = __builtin_amdgcn_exp2f(-x * LOG2E);
  return __builtin_amdgcn_rcpf(1.0f + e);
}
__device__ __forceinline__ float fast_tanh(float x) {
  float e = __builtin_amdgcn_exp2f(x * (2.0f * LOG2E));   // e^{2x}
  return 1.0f - 2.0f * __builtin_amdgcn_rcpf(e + 1.0f);
}

__device__ __forceinline__ unsigned short f2bf(float x) {  // RNE, no NaN inputs
  unsigned int u = __float_as_uint(x);
  u += 0x7FFFu + ((u >> 16) & 1u);
  return (unsigned short)(u >> 16);
}

#if __has_builtin(__builtin_amdgcn_sdot4)
#define SDOT4(a, b, c) __builtin_amdgcn_sdot4((a), (b), (c), false)
#else
__device__ __forceinline__ int sdot4_sw(int a, int b, int c) {
  c += ((a << 24) >> 24) * ((b << 24) >> 24);
  c += ((a << 16) >> 24) * ((b << 16) >> 24);
  c += ((a << 8) >> 24) * ((b << 8) >> 24);
  c += (a >> 24) * (b >> 24);
  return c;
}
#define SDOT4(a, b, c) sdot4_sw((a), (b), (c))
#endif

// ---------------------------------------------------------------------------
// GEMM: C[M,N] = A[M,K] * W[N,K]^T + bias0 + bias1.  A,W bf16 row-major
// (ushort). biases f32. 128x128 tile, BK=64, 4 waves (2x2), 16x16x32 bf16
// MFMA, reg-staged LDS.  K % 64 == 0.
// ---------------------------------------------------------------------------
__global__ __launch_bounds__(256) void gemm_bt(
    const unsigned short* __restrict__ A, int lda,
    const unsigned short* __restrict__ W, int ldw,
    const float* __restrict__ bias0,
    const float* __restrict__ bias1,
    void* __restrict__ C, int ldc, int c_f32, int K)
{
  __shared__ unsigned short As[128 * 64];
  __shared__ unsigned short Bs[128 * 64];
  const int tid = threadIdx.x;
  const int lane = tid & 63;
  const int w = tid >> 6;
  const int wm = w >> 1, wn = w & 1;
  const int bm = blockIdx.y * 128, bn = blockIdx.x * 128;

  f32x4 acc[4][4];
#pragma unroll
  for (int m = 0; m < 4; ++m)
#pragma unroll
    for (int n = 0; n < 4; ++n)
      acc[m][n] = (f32x4){0.f, 0.f, 0.f, 0.f};

  for (int k0 = 0; k0 < K; k0 += 64) {
    uint4 va[4], vb[4];
#pragma unroll
    for (int i = 0; i < 4; ++i) {
      int c = i * 256 + tid;                  // 16B chunk id within 128x64 tile
      va[i] = *(const uint4*)(A + (size_t)(bm + (c >> 3)) * lda + k0 + (c & 7) * 8);
      vb[i] = *(const uint4*)(W + (size_t)(bn + (c >> 3)) * ldw + k0 + (c & 7) * 8);
    }
    __syncthreads();                          // prev-iter LDS reads done
#pragma unroll
    for (int i = 0; i < 4; ++i) {
      int c = i * 256 + tid;
      *(uint4*)&As[c * 8] = va[i];
      *(uint4*)&Bs[c * 8] = vb[i];
    }
    __syncthreads();                          // tile ready
#pragma unroll
    for (int ks = 0; ks < 2; ++ks) {
      short8 a[4], b[4];
#pragma unroll
      for (int m = 0; m < 4; ++m)
        a[m] = *(const short8*)&As[(wm * 64 + m * 16 + (lane & 15)) * 64 + ks * 32 + (lane >> 4) * 8];
#pragma unroll
      for (int n = 0; n < 4; ++n)
        b[n] = *(const short8*)&Bs[(wn * 64 + n * 16 + (lane & 15)) * 64 + ks * 32 + (lane >> 4) * 8];
#pragma unroll
      for (int m = 0; m < 4; ++m)
#pragma unroll
        for (int n = 0; n < 4; ++n)
          acc[m][n] = __builtin_amdgcn_mfma_f32_16x16x32_bf16(a[m], b[n], acc[m][n], 0, 0, 0);
    }
  }

  // epilogue: C/D layout col=lane&15, row=(lane>>4)*4+reg
#pragma unroll
  for (int n = 0; n < 4; ++n) {
    int col = bn + wn * 64 + n * 16 + (lane & 15);
    float bsum = 0.f;
    if (bias0) bsum += bias0[col];
    if (bias1) bsum += bias1[col];
#pragma unroll
    for (int m = 0; m < 4; ++m) {
      int rbase = bm + wm * 64 + m * 16 + ((lane >> 4) * 4);
#pragma unroll
      for (int q = 0; q < 4; ++q) {
        float v = acc[m][n][q] + bsum;
        if (c_f32)
          ((float*)C)[(size_t)(rbase + q) * ldc + col] = v;
        else
          ((unsigned short*)C)[(size_t)(rbase + q) * ldc + col] = f2bf(v);
      }
    }
  }
}

// ---------------------------------------------------------------------------
// f32 -> bf16 conversions
// ---------------------------------------------------------------------------
__global__ void f2bf_flat(const float* __restrict__ src,
                          unsigned short* __restrict__ dst, int n4)
{
  int gid = blockIdx.x * 256 + threadIdx.x;
  if (gid >= n4) return;
  f32x4 v = ((const f32x4*)src)[gid];
  ushort4 o;
  o.x = f2bf(v.x); o.y = f2bf(v.y); o.z = f2bf(v.z); o.w = f2bf(v.w);
  ((ushort4*)dst)[gid] = o;
}

// copy f32 [rows, width] (contig) into bf16 [rows, dstLd] column block
__global__ void f2bf_strided(const float* __restrict__ src,
                             unsigned short* __restrict__ dst, int dstLd,
                             int chunkShift, int total)   // chunks of 4 elems
{
  int gid = blockIdx.x * 256 + threadIdx.x;
  if (gid >= total) return;
  int row = gid >> chunkShift;
  int ch = gid & ((1 << chunkShift) - 1);
  f32x4 v = ((const f32x4*)src)[(size_t)gid];
  ushort4 o;
  o.x = f2bf(v.x); o.y = f2bf(v.y); o.z = f2bf(v.z); o.w = f2bf(v.w);
  *(ushort4*)(dst + (size_t)row * dstLd + ch * 4) = o;
}

// ---------------------------------------------------------------------------
// Quantize LSTM recurrent weights [nrows x 256] f32 -> i8, TRANSPOSED output
// wqT[k*nrows + row] (k = packed-dword index 0..63), + per-row scale (max/127).
// One wave per row.
// ---------------------------------------------------------------------------
__global__ void quant_rows(const float* __restrict__ Wsrc,
                           int* __restrict__ wqT, float* __restrict__ scales,
                           int nrows)
{
  int row = blockIdx.x * 4 + (threadIdx.x >> 6);
  if (row >= nrows) return;
  int lane = threadIdx.x & 63;
  float v[4];
  float mx = 0.f;
#pragma unroll
  for (int i = 0; i < 4; ++i) {
    v[i] = Wsrc[(size_t)row * 256 + lane * 4 + i];
    mx = fmaxf(mx, fabsf(v[i]));
  }
#pragma unroll
  for (int d = 32; d >= 1; d >>= 1) mx = fmaxf(mx, __shfl_xor(mx, d));
  float inv = (mx > 0.f) ? 127.f / mx : 0.f;
  int packed = 0;
#pragma unroll
  for (int i = 0; i < 4; ++i) {
    int q = __float2int_rn(v[i] * inv);
    q = max(-127, min(127, q));
    packed |= (q & 0xFF) << (8 * i);
  }
  wqT[(size_t)lane * nrows + row] = packed;
  if (lane == 0) scales[row] = mx / 127.f;
}

// ---------------------------------------------------------------------------
// Sequential LSTM scan v2. T steps, H=256 (1024 gate rows), one 512-thread
// workgroup. Pairing: thread 2m owns rows m (i) and 512+m (g); thread 2m+1
// owns rows 256+m (f) and 768+m (o). u = i*tanh(g) crosses via shfl_xor(1).
// ONE raw s_barrier per step (lgkmcnt-only), double-buffered i8 h in LDS.
// ---------------------------------------------------------------------------
__global__ __launch_bounds__(512, 2) void lstm_scan(
    const float* __restrict__ xg,     // [T][1024]  (includes bih+bhh)
    const int* __restrict__ wqT,      // [64][1024] transposed packed i8
    const float* __restrict__ wsc,    // [1024] row scales (mx/127)
    unsigned short* __restrict__ hs,  // [T][ldh] bf16 output
    int T, int ldh)
{
  const int tid = threadIdx.x;
  const int m   = tid >> 1;           // unit index 0..255
  const int odd = tid & 1;
  const int r0  = m + (odd ? 256 : 0);      // i or f row
  const int r1  = m + (odd ? 768 : 512);    // g or o row

  int w0[64], w1[64];
#pragma unroll
  for (int k = 0; k < 64; ++k) w0[k] = wqT[k * 1024 + r0];
#pragma unroll
  for (int k = 0; k < 64; ++k) w1[k] = wqT[k * 1024 + r1];
  const float s0 = wsc[r0] * (1.f / 127.f);
  const float s1 = wsc[r1] * (1.f / 127.f);
  // second activation: even -> tanh(x) = 2*sig(2x)-1 ; odd -> sig(x)
  const float A2 = odd ? 1.f : 2.f;
  const float D2 = odd ? 0.f : -1.f;

  __shared__ __align__(16) int hq[2][64];   // h quantized i8, double buffered
  if (tid < 64) { hq[0][tid] = 0; hq[1][tid] = 0; }
  float c = 0.f;                            // cell state (odd threads)

  const float* pf0 = xg + r0;
  const float* pf1 = xg + r1;
  float xA0 = pf0[0],    xA1 = pf1[0];
  float xB0 = pf0[1024], xB1 = pf1[1024];
  pf0 += 2048; pf1 += 2048;                 // prefetch cursor at t+2

  asm volatile("s_waitcnt lgkmcnt(0)" ::: "memory");
  __builtin_amdgcn_s_barrier();
  asm volatile("" ::: "memory");

#define STEP(T_, RB, X0, X1)                                              \
  {                                                                       \
    float b0 = X0, b1 = X1;                                               \
    X0 = pf0[0]; X1 = pf1[0];   /* prefetch t+2 (overreads 2 rows, ok) */ \
    pf0 += 1024; pf1 += 1024;                                             \
    int a0 = 0, a1 = 0, a2 = 0, a3 = 0;                                   \
    const int4* hb = (const int4*)hq[RB];                                 \
    _Pragma("unroll")                                                     \
    for (int kk = 0; kk < 16; ++kk) {                                     \
      int4 hc = hb[kk];                      /* uniform ds_read_b128 */   \
      a0 = SDOT4(w0[4 * kk + 0], hc.x, a0);                               \
      a1 = SDOT4(w0[4 * kk + 1], hc.y, a1);                               \
      a0 = SDOT4(w0[4 * kk + 2], hc.z, a0);                               \
      a1 = SDOT4(w0[4 * kk + 3], hc.w, a1);                               \
      a2 = SDOT4(w1[4 * kk + 0], hc.x, a2);                               \
      a3 = SDOT4(w1[4 * kk + 1], hc.y, a3);                               \
      a2 = SDOT4(w1[4 * kk + 2], hc.z, a2);                               \
      a3 = SDOT4(w1[4 * kk + 3], hc.w, a3);                               \
    }                                                                     \
    float pa = (float)(a0 + a1) * s0 + b0;                                \
    float pb = (float)(a2 + a3) * s1 + b1;                                \
    float first  = fast_sigmoid(pa);              /* i (even) / f (odd) */\
    float second = A2 * fast_sigmoid(A2 * pb) + D2; /* g~ / o */          \
    float u  = first * second;                    /* even: i*g~ */        \
    float un = __shfl_xor(u, 1);                  /* odd gets even's u */ \
    c = first * c + un;                           /* odd: f*c + i*g~ */   \
    float h = second * fast_tanh(c);              /* odd: o*tanh(c) */    \
    if (odd) {                                                            \
      hs[(size_t)(T_) * ldh + m] = f2bf(h);                               \
      int q = __float2int_rn(h * 127.f);                                  \
      q = max(-127, min(127, q));                                         \
      ((char*)hq[RB ^ 1])[m] = (char)q;                                   \
    }                                                                     \
    asm volatile("s_waitcnt lgkmcnt(0)" ::: "memory");                    \
    __builtin_amdgcn_s_barrier();                                         \
    asm volatile("" ::: "memory");                                        \
  }

  for (int t = 0; t < T; t += 2) {
    STEP(t, 0, xA0, xA1);
    STEP(t + 1, 1, xB0, xB1);
  }
#undef STEP
}

// ---------------------------------------------------------------------------
// pair[n] = [nodes[e0[n]] | nodes[e1[n]]]  (bf16, 16B chunks)
// ---------------------------------------------------------------------------
__global__ void gather_pair(const unsigned short* __restrict__ nodes,
                            const int* __restrict__ edges,
                            unsigned short* __restrict__ pair)
{
  int gid = blockIdx.x * 256 + threadIdx.x;   // over 8192*64 chunks
  int row = gid >> 6;
  int ch = gid & 63;
  int side = ch >> 5;
  int k = ch & 31;
  int src = edges[row * 2 + side];
  uint4 v = ((const uint4*)(nodes + (size_t)src * 256))[k];
  ((uint4*)(pair + (size_t)row * 512))[ch] = v;
}

// ---------------------------------------------------------------------------
extern "C" void kernel_launch(void* const* d_in, const int* in_sizes, int n_in,
                              void* d_out, int out_size, void* d_ws, size_t ws_size,
                              hipStream_t stream)
{
  const float* inputs   = (const float*)d_in[0];
  const int*   edges    = (const int*)d_in[1];
  const float* memory   = (const float*)d_in[2];
  const float* Wi       = (const float*)d_in[3];
  const float* bi       = (const float*)d_in[4];
  const float* Wo       = (const float*)d_in[5];
  const float* bo       = (const float*)d_in[6];
  const float* edge_W   = (const float*)d_in[7];
  const float* edge_b   = (const float*)d_in[8];
  const float* node_Wih = (const float*)d_in[9];
  const float* node_Whh = (const float*)d_in[10];
  const float* node_bih = (const float*)d_in[11];
  const float* node_bhh = (const float*)d_in[12];
  const float* Wm       = (const float*)d_in[13];
  const float* bm       = (const float*)d_in[14];
  const float* cWih     = (const float*)d_in[15];
  const float* cWhh     = (const float*)d_in[16];
  const float* cbih     = (const float*)d_in[17];
  const float* cbhh     = (const float*)d_in[18];

  char* ws = (char*)d_ws;
  float*          xgbuf  = (float*)(ws + 0);                    // [8192,1024] f32
  unsigned short* Xbf    = (unsigned short*)(ws + 33554432);    // [8192,512]  inputs|edge_h
  unsigned short* Xc     = (unsigned short*)(ws + 41943040);    // [8192,640]  inputs|nodes2|memory
  unsigned short* nodes0 = (unsigned short*)(ws + 52428800);    // [8192,256]
  unsigned short* nodesA = (unsigned short*)(ws + 56623104);    // [8192,256]
  unsigned short* PAIR   = (unsigned short*)(ws + 60817408);    // [8192,512]
  unsigned short* hsC    = (unsigned short*)(ws + 69206016);    // [8192,256]
  unsigned short* WiB    = (unsigned short*)(ws + 73400320);    // 131072 B
  unsigned short* WoB    = (unsigned short*)(ws + 73531392);    // 131072 B
  unsigned short* eWB    = (unsigned short*)(ws + 73662464);    // 524288 B
  unsigned short* nWihB  = (unsigned short*)(ws + 74186752);    // 2097152 B
  unsigned short* WmB    = (unsigned short*)(ws + 76283904);    // 65536 B
  unsigned short* cWihB  = (unsigned short*)(ws + 76349440);    // 1310720 B
  int*            wqN0   = (int*)(ws + 77660160);               // [64][1024]
  int*            wqN1   = (int*)(ws + 77922304);               // [64][1024]
  int*            wqC    = (int*)(ws + 78184448);               // [64][1024]
  float*          scN0   = (float*)(ws + 78446592);             // [1024]
  float*          scN1   = (float*)(ws + 78450688);             // [1024]
  float*          scC    = (float*)(ws + 78454784);             // [1024]

  float* out0 = (float*)d_out;                // out     [8192,256] f32
  float* out1 = out0 + 8192 * 256;            // memvec  [8192,128] f32

  // --- prep: weight conversions + recurrent-weight quantization ---
  quant_rows<<<256, 256, 0, stream>>>(node_Whh, wqN0, scN0, 1024);
  quant_rows<<<256, 256, 0, stream>>>(node_Whh + 1024 * 256, wqN1, scN1, 1024);
  quant_rows<<<256, 256, 0, stream>>>(cWhh, wqC, scC, 1024);
  f2bf_flat<<<64, 256, 0, stream>>>(Wi, WiB, 16384);
  f2bf_flat<<<64, 256, 0, stream>>>(Wo, WoB, 16384);
  f2bf_flat<<<256, 256, 0, stream>>>(edge_W, eWB, 65536);
  f2bf_flat<<<1024, 256, 0, stream>>>(node_Wih, nWihB, 262144);
  f2bf_flat<<<32, 256, 0, stream>>>(Wm, WmB, 8192);
  f2bf_flat<<<640, 256, 0, stream>>>(cWih, cWihB, 163840);

  // --- static column blocks (inputs, memory) as bf16 ---
  f2bf_strided<<<2048, 256, 0, stream>>>(inputs, Xbf, 512, 6, 8192 * 64);
  f2bf_strided<<<2048, 256, 0, stream>>>(inputs, Xc, 640, 6, 8192 * 64);
  f2bf_strided<<<1024, 256, 0, stream>>>(memory, Xc + 512, 640, 5, 8192 * 32);

  // --- input layer: nodes0 = inputs @ Wi^T + bi ---
  gemm_bt<<<dim3(2, 64), 256, 0, stream>>>(Xbf, 512, WiB, 256, bi, nullptr,
                                           nodes0, 256, 0, 256);

  // --- relation r = 0 ---
  gather_pair<<<2048, 256, 0, stream>>>(nodes0, edges, PAIR);
  gemm_bt<<<dim3(2, 64), 256, 0, stream>>>(PAIR, 512, eWB, 512, edge_b, nullptr,
                                           Xbf + 256, 512, 0, 512);
  gemm_bt<<<dim3(8, 64), 256, 0, stream>>>(Xbf, 512, nWihB, 512, node_bih, node_bhh,
                                           xgbuf, 1024, 1, 512);
  lstm_scan<<<1, 512, 0, stream>>>(xgbuf, wqN0, scN0, nodesA, 8192, 256);

  // --- relation r = 1 (LSTM writes straight into Xc[:,256:512]) ---
  gather_pair<<<2048, 256, 0, stream>>>(nodesA, edges, PAIR);
  gemm_bt<<<dim3(2, 64), 256, 0, stream>>>(PAIR, 512, eWB + 256 * 512, 512,
                                           edge_b + 256, nullptr, Xbf + 256, 512, 0, 512);
  gemm_bt<<<dim3(8, 64), 256, 0, stream>>>(Xbf, 512, nWihB + 1024 * 512, 512,
                                           node_bih + 1024, node_bhh + 1024,
                                           xgbuf, 1024, 1, 512);
  lstm_scan<<<1, 512, 0, stream>>>(xgbuf, wqN1, scN1, Xc + 256, 8192, 640);

  // --- memory vector: nodes2 @ Wm^T + bm  (nodes2 = Xc[:,256:512]) ---
  gemm_bt<<<dim3(1, 64), 256, 0, stream>>>(Xc + 256, 640, WmB, 256, bm, nullptr,
                                           out1, 128, 1, 256);

  // --- controller LSTM ---
  gemm_bt<<<dim3(8, 64), 256, 0, stream>>>(Xc, 640, cWihB, 640, cbih, cbhh,
                                           xgbuf, 1024, 1, 640);
  lstm_scan<<<1, 512, 0, stream>>>(xgbuf, wqC, scC, hsC, 8192, 256);

  // --- output layer ---
  gemm_bt<<<dim3(2, 64), 256, 0, stream>>>(hsC, 256, WoB, 256, bo, nullptr,
                                           out0, 256, 1, 256);
}

// Round 5
// 19888.449 us; speedup vs baseline: 1.1287x; 1.0045x over previous
//
#include <hip/hip_runtime.h>

// GraphMemoryNetwork on MI355X — all reference tensors are float32.
// 7 small GEMMs (bf16 MFMA, f32 accum) + 3 sequential LSTM scans of T=8192
// steps. Scan v3: 512 threads, even/odd lane pairing, ONE raw s_barrier per
// step (lgkmcnt-only wait), double-buffered i8 h broadcast in LDS, Whh as
// int8 in ARCH VGPRs — amdgpu_waves_per_eu(2,2) pins the register budget to
// 256/wave so the 128 weight dwords stay out of AGPRs (round-3 VGPR_Count=84
// proved launch_bounds min-waves lets the allocator target 6 waves + AGPRs).

typedef __attribute__((ext_vector_type(8))) short short8;   // 8 bf16 (4 VGPRs)
typedef __attribute__((ext_vector_type(4))) float f32x4;

#define LOG2E 1.44269504088896340736f

__device__ __forceinline__ float fast_sigmoid(float x) {
  float e = __builtin_amdgcn_exp2f(-x * LOG2E);
  return __builtin_amdgcn_rcpf(1.0f + e);
}
__device__ __forceinline__ float fast_tanh(float x) {
  float e = __builtin_amdgcn_exp2f(x * (2.0f * LOG2E));   // e^{2x}
  return 1.0f - 2.0f * __builtin_amdgcn_rcpf(e + 1.0f);
}

__device__ __forceinline__ unsigned short f2bf(float x) {  // RNE, no NaN inputs
  unsigned int u = __float_as_uint(x);
  u += 0x7FFFu + ((u >> 16) & 1u);
  return (unsigned short)(u >> 16);
}

#if __has_builtin(__builtin_amdgcn_sdot4)
#define SDOT4(a, b, c) __builtin_amdgcn_sdot4((a), (b), (c), false)
#else
__device__ __forceinline__ int sdot4_sw(int a, int b, int c) {
  c += ((a << 24) >> 24) * ((b << 24) >> 24);
  c += ((a << 16) >> 24) * ((b << 16) >> 24);
  c += ((a << 8) >> 24) * ((b << 8) >> 24);
  c += (a >> 24) * (b >> 24);
  return c;
}
#define SDOT4(a, b, c) sdot4_sw((a), (b), (c))
#endif

// ---------------------------------------------------------------------------
// GEMM: C[M,N] = A[M,K] * W[N,K]^T + bias0 + bias1.  A,W bf16 row-major
// (ushort). biases f32. 128x128 tile, BK=64, 4 waves (2x2), 16x16x32 bf16
// MFMA, reg-staged LDS.  K % 64 == 0.
// ---------------------------------------------------------------------------
__global__ __launch_bounds__(256) void gemm_bt(
    const unsigned short* __restrict__ A, int lda,
    const unsigned short* __restrict__ W, int ldw,
    const float* __restrict__ bias0,
    const float* __restrict__ bias1,
    void* __restrict__ C, int ldc, int c_f32, int K)
{
  __shared__ unsigned short As[128 * 64];
  __shared__ unsigned short Bs[128 * 64];
  const int tid = threadIdx.x;
  const int lane = tid & 63;
  const int w = tid >> 6;
  const int wm = w >> 1, wn = w & 1;
  const int bm = blockIdx.y * 128, bn = blockIdx.x * 128;

  f32x4 acc[4][4];
#pragma unroll
  for (int m = 0; m < 4; ++m)
#pragma unroll
    for (int n = 0; n < 4; ++n)
      acc[m][n] = (f32x4){0.f, 0.f, 0.f, 0.f};

  for (int k0 = 0; k0 < K; k0 += 64) {
    uint4 va[4], vb[4];
#pragma unroll
    for (int i = 0; i < 4; ++i) {
      int c = i * 256 + tid;                  // 16B chunk id within 128x64 tile
      va[i] = *(const uint4*)(A + (size_t)(bm + (c >> 3)) * lda + k0 + (c & 7) * 8);
      vb[i] = *(const uint4*)(W + (size_t)(bn + (c >> 3)) * ldw + k0 + (c & 7) * 8);
    }
    __syncthreads();                          // prev-iter LDS reads done
#pragma unroll
    for (int i = 0; i < 4; ++i) {
      int c = i * 256 + tid;
      *(uint4*)&As[c * 8] = va[i];
      *(uint4*)&Bs[c * 8] = vb[i];
    }
    __syncthreads();                          // tile ready
#pragma unroll
    for (int ks = 0; ks < 2; ++ks) {
      short8 a[4], b[4];
#pragma unroll
      for (int m = 0; m < 4; ++m)
        a[m] = *(const short8*)&As[(wm * 64 + m * 16 + (lane & 15)) * 64 + ks * 32 + (lane >> 4) * 8];
#pragma unroll
      for (int n = 0; n < 4; ++n)
        b[n] = *(const short8*)&Bs[(wn * 64 + n * 16 + (lane & 15)) * 64 + ks * 32 + (lane >> 4) * 8];
#pragma unroll
      for (int m = 0; m < 4; ++m)
#pragma unroll
        for (int n = 0; n < 4; ++n)
          acc[m][n] = __builtin_amdgcn_mfma_f32_16x16x32_bf16(a[m], b[n], acc[m][n], 0, 0, 0);
    }
  }

  // epilogue: C/D layout col=lane&15, row=(lane>>4)*4+reg
#pragma unroll
  for (int n = 0; n < 4; ++n) {
    int col = bn + wn * 64 + n * 16 + (lane & 15);
    float bsum = 0.f;
    if (bias0) bsum += bias0[col];
    if (bias1) bsum += bias1[col];
#pragma unroll
    for (int m = 0; m < 4; ++m) {
      int rbase = bm + wm * 64 + m * 16 + ((lane >> 4) * 4);
#pragma unroll
      for (int q = 0; q < 4; ++q) {
        float v = acc[m][n][q] + bsum;
        if (c_f32)
          ((float*)C)[(size_t)(rbase + q) * ldc + col] = v;
        else
          ((unsigned short*)C)[(size_t)(rbase + q) * ldc + col] = f2bf(v);
      }
    }
  }
}

// ---------------------------------------------------------------------------
// f32 -> bf16 conversions
// ---------------------------------------------------------------------------
__global__ void f2bf_flat(const float* __restrict__ src,
                          unsigned short* __restrict__ dst, int n4)
{
  int gid = blockIdx.x * 256 + threadIdx.x;
  if (gid >= n4) return;
  f32x4 v = ((const f32x4*)src)[gid];
  ushort4 o;
  o.x = f2bf(v.x); o.y = f2bf(v.y); o.z = f2bf(v.z); o.w = f2bf(v.w);
  ((ushort4*)dst)[gid] = o;
}

// copy f32 [rows, width] (contig) into bf16 [rows, dstLd] column block
__global__ void f2bf_strided(const float* __restrict__ src,
                             unsigned short* __restrict__ dst, int dstLd,
                             int chunkShift, int total)   // chunks of 4 elems
{
  int gid = blockIdx.x * 256 + threadIdx.x;
  if (gid >= total) return;
  int row = gid >> chunkShift;
  int ch = gid & ((1 << chunkShift) - 1);
  f32x4 v = ((const f32x4*)src)[(size_t)gid];
  ushort4 o;
  o.x = f2bf(v.x); o.y = f2bf(v.y); o.z = f2bf(v.z); o.w = f2bf(v.w);
  *(ushort4*)(dst + (size_t)row * dstLd + ch * 4) = o;
}

// ---------------------------------------------------------------------------
// Quantize LSTM recurrent weights [nrows x 256] f32 -> i8, TRANSPOSED output
// wqT[k*nrows + row] (k = packed-dword index 0..63), + per-row scale (max/127).
// One wave per row.
// ---------------------------------------------------------------------------
__global__ void quant_rows(const float* __restrict__ Wsrc,
                           int* __restrict__ wqT, float* __restrict__ scales,
                           int nrows)
{
  int row = blockIdx.x * 4 + (threadIdx.x >> 6);
  if (row >= nrows) return;
  int lane = threadIdx.x & 63;
  float v[4];
  float mx = 0.f;
#pragma unroll
  for (int i = 0; i < 4; ++i) {
    v[i] = Wsrc[(size_t)row * 256 + lane * 4 + i];
    mx = fmaxf(mx, fabsf(v[i]));
  }
#pragma unroll
  for (int d = 32; d >= 1; d >>= 1) mx = fmaxf(mx, __shfl_xor(mx, d));
  float inv = (mx > 0.f) ? 127.f / mx : 0.f;
  int packed = 0;
#pragma unroll
  for (int i = 0; i < 4; ++i) {
    int q = __float2int_rn(v[i] * inv);
    q = max(-127, min(127, q));
    packed |= (q & 0xFF) << (8 * i);
  }
  wqT[(size_t)lane * nrows + row] = packed;
  if (lane == 0) scales[row] = mx / 127.f;
}

// ---------------------------------------------------------------------------
// Sequential LSTM scan v3. T steps, H=256 (1024 gate rows), one 512-thread
// workgroup pinned at 2 waves/EU (256-VGPR budget -> weights arch-resident).
// Pairing: thread 2m owns rows m (i) and 512+m (g); thread 2m+1 owns rows
// 256+m (f) and 768+m (o). u = i*tanh(g) crosses via shfl_xor(1).
// ONE raw s_barrier per step (lgkmcnt-only), double-buffered i8 h in LDS.
// ---------------------------------------------------------------------------
__global__ __launch_bounds__(512)
__attribute__((amdgpu_waves_per_eu(2, 2)))
void lstm_scan(
    const float* __restrict__ xg,     // [T][1024]  (includes bih+bhh)
    const int* __restrict__ wqT,      // [64][1024] transposed packed i8
    const float* __restrict__ wsc,    // [1024] row scales (mx/127)
    unsigned short* __restrict__ hs,  // [T][ldh] bf16 output
    int T, int ldh)
{
  const int tid = threadIdx.x;
  const int m   = tid >> 1;           // unit index 0..255
  const int odd = tid & 1;
  const int r0  = m + (odd ? 256 : 0);      // i or f row
  const int r1  = m + (odd ? 768 : 512);    // g or o row

  int w0[64], w1[64];
#pragma unroll
  for (int k = 0; k < 64; ++k) w0[k] = wqT[k * 1024 + r0];
#pragma unroll
  for (int k = 0; k < 64; ++k) w1[k] = wqT[k * 1024 + r1];
  const float s0 = wsc[r0] * (1.f / 127.f);
  const float s1 = wsc[r1] * (1.f / 127.f);
  // second activation: even -> tanh(x) = 2*sig(2x)-1 ; odd -> sig(x)
  const float A2 = odd ? 1.f : 2.f;
  const float D2 = odd ? 0.f : -1.f;

  __shared__ __align__(16) int hq[2][64];   // h quantized i8, double buffered
  if (tid < 64) { hq[0][tid] = 0; hq[1][tid] = 0; }
  float c = 0.f;                            // cell state (odd threads)

  // uniform scalar cursor + per-thread fixed offsets (saves 64-bit VGPR adds)
  const float* xp = xg;
  float xA0 = xp[r0],        xA1 = xp[r1];
  float xB0 = xp[1024 + r0], xB1 = xp[1024 + r1];
  xp += 2048;                               // prefetch cursor at t+2

  asm volatile("s_waitcnt lgkmcnt(0)" ::: "memory");
  __builtin_amdgcn_s_barrier();
  asm volatile("" ::: "memory");

#define STEP(T_, RB, X0, X1)                                              \
  {                                                                       \
    float b0 = X0, b1 = X1;                                               \
    X0 = xp[r0]; X1 = xp[r1];   /* prefetch t+2 (overreads 2 rows, ok) */ \
    xp += 1024;                                                           \
    int a0 = 0, a1 = 0, a2 = 0, a3 = 0;                                   \
    const int4* hb = (const int4*)hq[RB];                                 \
    _Pragma("unroll")                                                     \
    for (int kk = 0; kk < 16; ++kk) {                                     \
      int4 hc = hb[kk];                      /* uniform ds_read_b128 */   \
      a0 = SDOT4(w0[4 * kk + 0], hc.x, a0);                               \
      a1 = SDOT4(w0[4 * kk + 1], hc.y, a1);                               \
      a0 = SDOT4(w0[4 * kk + 2], hc.z, a0);                               \
      a1 = SDOT4(w0[4 * kk + 3], hc.w, a1);                               \
      a2 = SDOT4(w1[4 * kk + 0], hc.x, a2);                               \
      a3 = SDOT4(w1[4 * kk + 1], hc.y, a3);                               \
      a2 = SDOT4(w1[4 * kk + 2], hc.z, a2);                               \
      a3 = SDOT4(w1[4 * kk + 3], hc.w, a3);                               \
    }                                                                     \
    float pa = (float)(a0 + a1) * s0 + b0;                                \
    float pb = (float)(a2 + a3) * s1 + b1;                                \
    float first  = fast_sigmoid(pa);              /* i (even) / f (odd) */\
    float second = A2 * fast_sigmoid(A2 * pb) + D2; /* g~ / o */          \
    float u  = first * second;                    /* even: i*g~ */        \
    float un = __shfl_xor(u, 1);                  /* odd gets even's u */ \
    c = first * c + un;                           /* odd: f*c + i*g~ */   \
    float h = second * fast_tanh(c);              /* odd: o*tanh(c) */    \
    if (odd) {                                                            \
      hs[(size_t)(T_) * ldh + m] = f2bf(h);                               \
      int q = __float2int_rn(h * 127.f);                                  \
      q = max(-127, min(127, q));                                         \
      ((char*)hq[RB ^ 1])[m] = (char)q;                                   \
    }                                                                     \
    asm volatile("s_waitcnt lgkmcnt(0)" ::: "memory");                    \
    __builtin_amdgcn_s_barrier();                                         \
    asm volatile("" ::: "memory");                                        \
  }

  for (int t = 0; t < T; t += 2) {
    STEP(t, 0, xA0, xA1);
    STEP(t + 1, 1, xB0, xB1);
  }
#undef STEP
}

// ---------------------------------------------------------------------------
// pair[n] = [nodes[e0[n]] | nodes[e1[n]]]  (bf16, 16B chunks)
// ---------------------------------------------------------------------------
__global__ void gather_pair(const unsigned short* __restrict__ nodes,
                            const int* __restrict__ edges,
                            unsigned short* __restrict__ pair)
{
  int gid = blockIdx.x * 256 + threadIdx.x;   // over 8192*64 chunks
  int row = gid >> 6;
  int ch = gid & 63;
  int side = ch >> 5;
  int k = ch & 31;
  int src = edges[row * 2 + side];
  uint4 v = ((const uint4*)(nodes + (size_t)src * 256))[k];
  ((uint4*)(pair + (size_t)row * 512))[ch] = v;
}

// ---------------------------------------------------------------------------
extern "C" void kernel_launch(void* const* d_in, const int* in_sizes, int n_in,
                              void* d_out, int out_size, void* d_ws, size_t ws_size,
                              hipStream_t stream)
{
  const float* inputs   = (const float*)d_in[0];
  const int*   edges    = (const int*)d_in[1];
  const float* memory   = (const float*)d_in[2];
  const float* Wi       = (const float*)d_in[3];
  const float* bi       = (const float*)d_in[4];
  const float* Wo       = (const float*)d_in[5];
  const float* bo       = (const float*)d_in[6];
  const float* edge_W   = (const float*)d_in[7];
  const float* edge_b   = (const float*)d_in[8];
  const float* node_Wih = (const float*)d_in[9];
  const float* node_Whh = (const float*)d_in[10];
  const float* node_bih = (const float*)d_in[11];
  const float* node_bhh = (const float*)d_in[12];
  const float* Wm       = (const float*)d_in[13];
  const float* bm       = (const float*)d_in[14];
  const float* cWih     = (const float*)d_in[15];
  const float* cWhh     = (const float*)d_in[16];
  const float* cbih     = (const float*)d_in[17];
  const float* cbhh     = (const float*)d_in[18];

  char* ws = (char*)d_ws;
  float*          xgbuf  = (float*)(ws + 0);                    // [8192,1024] f32
  unsigned short* Xbf    = (unsigned short*)(ws + 33554432);    // [8192,512]  inputs|edge_h
  unsigned short* Xc     = (unsigned short*)(ws + 41943040);    // [8192,640]  inputs|nodes2|memory
  unsigned short* nodes0 = (unsigned short*)(ws + 52428800);    // [8192,256]
  unsigned short* nodesA = (unsigned short*)(ws + 56623104);    // [8192,256]
  unsigned short* PAIR   = (unsigned short*)(ws + 60817408);    // [8192,512]
  unsigned short* hsC    = (unsigned short*)(ws + 69206016);    // [8192,256]
  unsigned short* WiB    = (unsigned short*)(ws + 73400320);    // 131072 B
  unsigned short* WoB    = (unsigned short*)(ws + 73531392);    // 131072 B
  unsigned short* eWB    = (unsigned short*)(ws + 73662464);    // 524288 B
  unsigned short* nWihB  = (unsigned short*)(ws + 74186752);    // 2097152 B
  unsigned short* WmB    = (unsigned short*)(ws + 76283904);    // 65536 B
  unsigned short* cWihB  = (unsigned short*)(ws + 76349440);    // 1310720 B
  int*            wqN0   = (int*)(ws + 77660160);               // [64][1024]
  int*            wqN1   = (int*)(ws + 77922304);               // [64][1024]
  int*            wqC    = (int*)(ws + 78184448);               // [64][1024]
  float*          scN0   = (float*)(ws + 78446592);             // [1024]
  float*          scN1   = (float*)(ws + 78450688);             // [1024]
  float*          scC    = (float*)(ws + 78454784);             // [1024]

  float* out0 = (float*)d_out;                // out     [8192,256] f32
  float* out1 = out0 + 8192 * 256;            // memvec  [8192,128] f32

  // --- prep: weight conversions + recurrent-weight quantization ---
  quant_rows<<<256, 256, 0, stream>>>(node_Whh, wqN0, scN0, 1024);
  quant_rows<<<256, 256, 0, stream>>>(node_Whh + 1024 * 256, wqN1, scN1, 1024);
  quant_rows<<<256, 256, 0, stream>>>(cWhh, wqC, scC, 1024);
  f2bf_flat<<<64, 256, 0, stream>>>(Wi, WiB, 16384);
  f2bf_flat<<<64, 256, 0, stream>>>(Wo, WoB, 16384);
  f2bf_flat<<<256, 256, 0, stream>>>(edge_W, eWB, 65536);
  f2bf_flat<<<1024, 256, 0, stream>>>(node_Wih, nWihB, 262144);
  f2bf_flat<<<32, 256, 0, stream>>>(Wm, WmB, 8192);
  f2bf_flat<<<640, 256, 0, stream>>>(cWih, cWihB, 163840);

  // --- static column blocks (inputs, memory) as bf16 ---
  f2bf_strided<<<2048, 256, 0, stream>>>(inputs, Xbf, 512, 6, 8192 * 64);
  f2bf_strided<<<2048, 256, 0, stream>>>(inputs, Xc, 640, 6, 8192 * 64);
  f2bf_strided<<<1024, 256, 0, stream>>>(memory, Xc + 512, 640, 5, 8192 * 32);

  // --- input layer: nodes0 = inputs @ Wi^T + bi ---
  gemm_bt<<<dim3(2, 64), 256, 0, stream>>>(Xbf, 512, WiB, 256, bi, nullptr,
                                           nodes0, 256, 0, 256);

  // --- relation r = 0 ---
  gather_pair<<<2048, 256, 0, stream>>>(nodes0, edges, PAIR);
  gemm_bt<<<dim3(2, 64), 256, 0, stream>>>(PAIR, 512, eWB, 512, edge_b, nullptr,
                                           Xbf + 256, 512, 0, 512);
  gemm_bt<<<dim3(8, 64), 256, 0, stream>>>(Xbf, 512, nWihB, 512, node_bih, node_bhh,
                                           xgbuf, 1024, 1, 512);
  lstm_scan<<<1, 512, 0, stream>>>(xgbuf, wqN0, scN0, nodesA, 8192, 256);

  // --- relation r = 1 (LSTM writes straight into Xc[:,256:512]) ---
  gather_pair<<<2048, 256, 0, stream>>>(nodesA, edges, PAIR);
  gemm_bt<<<dim3(2, 64), 256, 0, stream>>>(PAIR, 512, eWB + 256 * 512, 512,
                                           edge_b + 256, nullptr, Xbf + 256, 512, 0, 512);
  gemm_bt<<<dim3(8, 64), 256, 0, stream>>>(Xbf, 512, nWihB + 1024 * 512, 512,
                                           node_bih + 1024, node_bhh + 1024,
                                           xgbuf, 1024, 1, 512);
  lstm_scan<<<1, 512, 0, stream>>>(xgbuf, wqN1, scN1, Xc + 256, 8192, 640);

  // --- memory vector: nodes2 @ Wm^T + bm  (nodes2 = Xc[:,256:512]) ---
  gemm_bt<<<dim3(1, 64), 256, 0, stream>>>(Xc + 256, 640, WmB, 256, bm, nullptr,
                                           out1, 128, 1, 256);

  // --- controller LSTM ---
  gemm_bt<<<dim3(8, 64), 256, 0, stream>>>(Xc, 640, cWihB, 640, cbih, cbhh,
                                           xgbuf, 1024, 1, 640);
  lstm_scan<<<1, 512, 0, stream>>>(xgbuf, wqC, scC, hsC, 8192, 256);

  // --- output layer ---
  gemm_bt<<<dim3(2, 64), 256, 0, stream>>>(hsC, 256, WoB, 256, bo, nullptr,
                                           out0, 256, 1, 256);
}